// Round 11
// baseline (735.893 us; speedup 1.0000x reference)
//
#include <hip/hip_runtime.h>
#include <math.h>

#define NIMG 32
#define NB3  771             // 257 rings * 3 sums
#define PI_F 3.14159265358979323846f

// ---------------------------------------------------------------------------
__device__ __forceinline__ float2 cadd(float2 a, float2 b){ return make_float2(a.x+b.x, a.y+b.y); }
__device__ __forceinline__ float2 csub(float2 a, float2 b){ return make_float2(a.x-b.x, a.y-b.y); }
__device__ __forceinline__ float2 cmul(float2 a, float2 b){ return make_float2(a.x*b.x - a.y*b.y, a.x*b.y + a.y*b.x); }
__device__ __forceinline__ float2 cmul_mi(float2 a){ return make_float2(a.y, -a.x); }   // * (-i)
__device__ __forceinline__ float2 tw(const float2* T, int m){ return T[m + (m >> 3)]; }
__device__ __forceinline__ int   swz(int pos){ return pos + (pos >> 3); }

// 8-point DFT (DIF, natural-order outputs), e^{-2pi i/8} convention
__device__ __forceinline__ void dft8(float2* x) {
    const float c = 0.70710678118654752f;
    float2 u0 = cadd(x[0], x[4]), u1 = cadd(x[1], x[5]);
    float2 u2 = cadd(x[2], x[6]), u3 = cadd(x[3], x[7]);
    float2 v0 = csub(x[0], x[4]);
    float2 d1 = csub(x[1], x[5]);
    float2 v1 = make_float2(c*(d1.x + d1.y), c*(d1.y - d1.x));
    float2 d2 = csub(x[2], x[6]);
    float2 v2 = make_float2(d2.y, -d2.x);
    float2 d3 = csub(x[3], x[7]);
    float2 v3 = make_float2(-c*(d3.x - d3.y), -c*(d3.x + d3.y));
    float2 e0 = cadd(u0,u2), e1 = cadd(u1,u3);
    float2 f0 = csub(u0,u2), f1 = cmul_mi(csub(u1,u3));
    float2 g0 = cadd(v0,v2), g1 = cadd(v1,v3);
    float2 h0 = csub(v0,v2), h1 = cmul_mi(csub(v1,v3));
    x[0] = cadd(e0,e1); x[4] = csub(e0,e1);
    x[2] = cadd(f0,f1); x[6] = csub(f0,f1);
    x[1] = cadd(g0,g1); x[5] = csub(g0,g1);
    x[3] = cadd(h0,h1); x[7] = csub(h0,h1);
}

// ---------------------------------------------------------------------------
// Per-wave 512-pt radix-8 DIF FFT, barrier-free (wave-private 576-slot LDS
// scratch; one wave's LDS ops execute in order). Thread J enters with
// X[q] = x[J + 64q], exits with X[k] = F(64k + r), r = 8*(J&7) + (J>>3).
// ---------------------------------------------------------------------------
__device__ __forceinline__ void wave_fft512(float2* X, float2* Sw,
                                            const float2* T, int J) {
    dft8(X);
#pragma unroll
    for (int k = 1; k < 8; ++k) X[k] = cmul(X[k], tw(T, J * k));
    const int jj = J + (J >> 3);
#pragma unroll
    for (int k = 0; k < 8; ++k) Sw[jj + 72*k] = X[k];

    const int j2 = J & 7;
    const int bb = 72 * (J >> 3) + j2;
#pragma unroll
    for (int q = 0; q < 8; ++q) X[q] = Sw[bb + 9*q];
    dft8(X);
#pragma unroll
    for (int k = 1; k < 8; ++k) X[k] = cmul(X[k], tw(T, 8 * j2 * k));
#pragma unroll
    for (int k = 0; k < 8; ++k) Sw[bb + 9*k] = X[k];

#pragma unroll
    for (int q = 0; q < 8; ++q) X[q] = Sw[9*J + q];
    dft8(X);
}

// ---------------------------------------------------------------------------
// Row pass: 4 waves/block; wave w does rows grp*8+w and grp*8+w+4.
// NEW: float4 global loads (16 B/lane, 8 total) -> raw park in wave-private
// LDS (interleaved complex) -> strided LDS read into FFT registers.
// Transposed store Zt[kx][y] via the 3-barrier cross-wave rounds (as R8).
// ---------------------------------------------------------------------------
__global__ __launch_bounds__(256, 4) void fft_rows_T(const float* __restrict__ xr,
                                                     const float* __restrict__ yr,
                                                     float2* __restrict__ Zt,
                                                     float* __restrict__ sums,
                                                     int big) {
    __shared__ float2 S[4 * 576];   // 18,432 B
    __shared__ float2 T[576];       //  4,608 B
    const int t = threadIdx.x, w = t >> 6, J = t & 63;
    const int im = blockIdx.x >> 6, grp = blockIdx.x & 63;

#pragma unroll
    for (int i = 0; i < 2; ++i) {
        const int m = t + 256 * i;
        float s, c;
        __sincosf(-2.0f * PI_F * (float)m / 512.0f, &s, &c);
        T[m + (m >> 3)] = make_float2(c, s);
    }
    if (!big) {                      // small-ws fallback: zero shared ring slices
        const int idx = blockIdx.x * 256 + t;
        if (idx < NIMG * 8 * NB3) sums[idx] = 0.0f;
    }

    const size_t b0 = ((size_t)(im * 512 + grp * 8 + w)) << 9;
    const float4* x40 = (const float4*)(xr + b0);
    const float4* y40 = (const float4*)(yr + b0);
    const float4* x41 = (const float4*)(xr + b0 + 2048);
    const float4* y41 = (const float4*)(yr + b0 + 2048);
    // 8 x 16B loads, all issued up front
    float4 aX0 = x40[J], aX1 = x40[J + 64];
    float4 aY0 = y40[J], aY1 = y40[J + 64];
    float4 bX0 = x41[J], bX1 = x41[J + 64];
    float4 bY0 = y41[J], bY1 = y41[J + 64];
    __syncthreads();                       // T ready

    float2* Sw = S + w * 576;
    float2 X0[8], X1[8];

    // --- row 0: raw park (interleaved complex), strided read ---
    {
        const int p0 = 4 * J,        s0 = p0 + (p0 >> 3);
        const int p1 = 4 * J + 256,  s1 = p1 + (p1 >> 3);
        Sw[s0+0] = make_float2(aX0.x, aY0.x); Sw[s0+1] = make_float2(aX0.y, aY0.y);
        Sw[s0+2] = make_float2(aX0.z, aY0.z); Sw[s0+3] = make_float2(aX0.w, aY0.w);
        Sw[s1+0] = make_float2(aX1.x, aY1.x); Sw[s1+1] = make_float2(aX1.y, aY1.y);
        Sw[s1+2] = make_float2(aX1.z, aY1.z); Sw[s1+3] = make_float2(aX1.w, aY1.w);
#pragma unroll
        for (int q = 0; q < 8; ++q) X0[q] = Sw[swz(J + 64*q)];
    }
    // --- row 1 ---
    {
        const int p0 = 4 * J,        s0 = p0 + (p0 >> 3);
        const int p1 = 4 * J + 256,  s1 = p1 + (p1 >> 3);
        Sw[s0+0] = make_float2(bX0.x, bY0.x); Sw[s0+1] = make_float2(bX0.y, bY0.y);
        Sw[s0+2] = make_float2(bX0.z, bY0.z); Sw[s0+3] = make_float2(bX0.w, bY0.w);
        Sw[s1+0] = make_float2(bX1.x, bY1.x); Sw[s1+1] = make_float2(bX1.y, bY1.y);
        Sw[s1+2] = make_float2(bX1.z, bY1.z); Sw[s1+3] = make_float2(bX1.w, bY1.w);
#pragma unroll
        for (int q = 0; q < 8; ++q) X1[q] = Sw[swz(J + 64*q)];
    }

    wave_fft512(X0, Sw, T, J);
    wave_fft512(X1, Sw, T, J);

    const int r = ((J & 7) << 3) | (J >> 3);

    // round 1: rows 0..3 natural order in own region, cross-wave gather
#pragma unroll
    for (int k = 0; k < 8; ++k) Sw[64*k + r] = X0[k];
    __syncthreads();
    float2 eA[4], eB[4];
#pragma unroll
    for (int j = 0; j < 4; ++j) { eA[j] = S[j*576 + t]; eB[j] = S[j*576 + t + 256]; }
    __syncthreads();
    // round 2: rows 4..7
#pragma unroll
    for (int k = 0; k < 8; ++k) Sw[64*k + r] = X1[k];
    __syncthreads();

    const size_t zb = ((size_t)im << 18) + (grp << 3);
    {
        float4* o = (float4*)(Zt + zb + ((size_t)t << 9));
        float2 f0 = S[0*576 + t], f1 = S[1*576 + t];
        float2 f2 = S[2*576 + t], f3 = S[3*576 + t];
        o[0] = make_float4(eA[0].x, eA[0].y, eA[1].x, eA[1].y);
        o[1] = make_float4(eA[2].x, eA[2].y, eA[3].x, eA[3].y);
        o[2] = make_float4(f0.x, f0.y, f1.x, f1.y);
        o[3] = make_float4(f2.x, f2.y, f3.x, f3.y);
    }
    {
        float4* o = (float4*)(Zt + zb + ((size_t)(t + 256) << 9));
        float2 f0 = S[0*576 + t + 256], f1 = S[1*576 + t + 256];
        float2 f2 = S[2*576 + t + 256], f3 = S[3*576 + t + 256];
        o[0] = make_float4(eB[0].x, eB[0].y, eB[1].x, eB[1].y);
        o[1] = make_float4(eB[2].x, eB[2].y, eB[3].x, eB[3].y);
        o[2] = make_float4(f0.x, f0.y, f1.x, f1.y);
        o[3] = make_float4(f2.x, f2.y, f3.x, f3.y);
    }
}

// ---------------------------------------------------------------------------
// Fused column FFT + rings (R8 structure, float4 loads). Wave w of block g
// owns mirror pair p = 4g+w: p=0 -> cols (0,256) self-mirror; p>=1 ->
// (p, 512-p), where pixel (p,ky) and (512-p,512-ky) share ring AND values
// {P0[ky], P1[512-ky]} -> lane-local, no shuffles. Run-merged LDS atomics.
// ---------------------------------------------------------------------------
__global__ __launch_bounds__(256, 4) void fft_cols_rings(const float2* __restrict__ Zt,
                                                         float* __restrict__ sums,
                                                         int big) {
    __shared__ float2 S[8 * 576];      // 36,864 B
    __shared__ float2 T[576];          //  4,608 B
    __shared__ float  bins[258 * 3];   //  3,096 B
    const int t = threadIdx.x, w = t >> 6, J = t & 63;
    const int im = blockIdx.x >> 6, g = blockIdx.x & 63;
    const int p = 4 * g + w;

#pragma unroll
    for (int i = 0; i < 2; ++i) {
        const int m = t + 256 * i;
        float s, c;
        __sincosf(-2.0f * PI_F * (float)m / 512.0f, &s, &c);
        T[m + (m >> 3)] = make_float2(c, s);
    }
    for (int i = t; i < 258 * 3; i += 256) bins[i] = 0.0f;

    const int c0 = (p == 0) ? 0   : p;
    const int c1 = (p == 0) ? 256 : 512 - p;
    const float4* f40 = (const float4*)(Zt + ((size_t)im << 18) + ((size_t)c0 << 9));
    const float4* f41 = (const float4*)(Zt + ((size_t)im << 18) + ((size_t)c1 << 9));
    float4 L0[4], L1[4];
#pragma unroll
    for (int i = 0; i < 4; ++i) { L0[i] = f40[J + 64*i]; L1[i] = f41[J + 64*i]; }
    __syncthreads();                       // T ready, bins zeroed

    float2* A = S + (2*w) * 576;
    float2* B = A + 576;
    const int r  = ((J & 7) << 3) | (J >> 3);
    const int pk = r + (r >> 3);           // swz(64k + r) = 72k + pk
    float2 X0[8], X1[8];

    // col A: raw park -> strided read -> FFT -> natural-order park
#pragma unroll
    for (int i = 0; i < 4; ++i) {
        const int pp = 2 * (J + 64*i), ss = pp + (pp >> 3);
        A[ss]   = make_float2(L0[i].x, L0[i].y);
        A[ss+1] = make_float2(L0[i].z, L0[i].w);
    }
#pragma unroll
    for (int q = 0; q < 8; ++q) X0[q] = A[swz(J + 64*q)];
    wave_fft512(X0, A, T, J);
#pragma unroll
    for (int k = 0; k < 8; ++k) A[72*k + pk] = X0[k];
    // col B
#pragma unroll
    for (int i = 0; i < 4; ++i) {
        const int pp = 2 * (J + 64*i), ss = pp + (pp >> 3);
        B[ss]   = make_float2(L1[i].x, L1[i].y);
        B[ss+1] = make_float2(L1[i].z, L1[i].w);
    }
#pragma unroll
    for (int q = 0; q < 8; ++q) X1[q] = B[swz(J + 64*q)];
    wave_fft512(X1, B, T, J);
#pragma unroll
    for (int k = 0; k < 8; ++k) B[72*k + pk] = X1[k];

    // ---- ring phase: lane-local reads, run-merged LDS-atomic deposits
    const float scale = 1.0f / (512.0f * 512.0f);
    auto pix = [&](float2 zk, float2 zm, float& av, float& c1v, float& c2v) {
        float f1r = 0.5f * (zk.x + zm.x) * scale;
        float f1i = 0.5f * (zk.y - zm.y) * scale;
        float f2r = 0.5f * (zk.y + zm.y) * scale;
        float f2i = 0.5f * (zm.x - zk.x) * scale;
        av  = f1r * f2r + f1i * f2i;
        c1v = f1r * f1r + f1i * f1i;
        c2v = f2r * f2r + f2i * f2i;
    };
    auto flush = [&](int ring, float a, float b, float c) {
        if (ring >= 0 && ring <= 256) {
            unsafeAtomicAdd(&bins[ring*3+0], a);
            unsafeAtomicAdd(&bins[ring*3+1], b);
            unsafeAtomicAdd(&bins[ring*3+2], c);
        }
    };

    if (p == 0) {
        int cur0 = -1, cur1 = -1;
        float a0 = 0, b0 = 0, c0v = 0, a1 = 0, b1 = 0, c1v = 0;
#pragma unroll
        for (int i = 0; i < 8; ++i) {
            const int ky  = 8*J + i;
            const int kyp = (512 - ky) & 511;
            float2 zk0 = A[swz(ky)], zm0 = A[swz(kyp)];
            float2 zk1 = B[swz(ky)], zm1 = B[swz(kyp)];
            const float fk = (ky < 256) ? (float)ky : (float)(ky - 512);
            float av, cv, dv;
            pix(zk0, zm0, av, cv, dv);                 // col 0, fy = 0
            int rr = (int)rintf(fabsf(fk)); if (rr > 256) rr = 257;
            if (rr != cur0) { flush(cur0, a0, b0, c0v); cur0 = rr; a0 = av; b0 = cv; c0v = dv; }
            else            { a0 += av; b0 += cv; c0v += dv; }
            pix(zk1, zm1, av, cv, dv);                 // col 256, fy = 256
            rr = (int)rintf(sqrtf(fk*fk + 65536.0f)); if (rr > 256) rr = 257;
            if (rr != cur1) { flush(cur1, a1, b1, c1v); cur1 = rr; a1 = av; b1 = cv; c1v = dv; }
            else            { a1 += av; b1 += cv; c1v += dv; }
        }
        flush(cur0, a0, b0, c0v);
        flush(cur1, a1, b1, c1v);
    } else {
        const float fy2 = (float)p * (float)p;
        int curR = -1;
        float sA = 0, sB = 0, sC = 0;
#pragma unroll
        for (int i = 0; i < 8; ++i) {
            const int ky  = 8*J + i;
            const int kyp = (512 - ky) & 511;
            float2 zk = A[swz(ky)];          // P0[ky]
            float2 zm = B[swz(kyp)];         // P1[512-ky]
            float a1v, b1v, d1v, a2v, b2v, d2v;
            pix(zk, zm, a1v, b1v, d1v);      // (p, ky)         partner (512-p, 512-ky)
            pix(zm, zk, a2v, b2v, d2v);      // (512-p, 512-ky) partner (p, ky)
            const float fk = (ky < 256) ? (float)ky : (float)(ky - 512);
            int rr = (int)rintf(sqrtf(fk*fk + fy2)); if (rr > 256) rr = 257;
            const float aa = a1v + a2v, bb = b1v + b2v, cc = d1v + d2v;
            if (rr != curR) { flush(curR, sA, sB, sC); curR = rr; sA = aa; sB = bb; sC = cc; }
            else            { sA += aa; sB += bb; sC += cc; }
        }
        flush(curR, sA, sB, sC);
    }
    __syncthreads();

    if (big) {
        float* dst = sums + (size_t)blockIdx.x * NB3;          // private slice
        for (int i = t; i < NB3; i += 256) dst[i] = bins[i];
    } else {
        float* dst = sums + (size_t)(im * 8 + (g & 7)) * NB3;  // shared slice
        for (int i = t; i < NB3; i += 256) unsafeAtomicAdd(&dst[i], bins[i]);
    }
}

// ---------------------------------------------------------------------------
// Finalize, SINGLE block: sum nsl slices per (image, ring), mean of (1-frc)^2,
// plain store (no memset of d_out needed, no global atomics).
// C_i ring sums are exactly 0 by k -> -k antisymmetry; dropped.
// ---------------------------------------------------------------------------
__global__ __launch_bounds__(256) void finalize(const float* __restrict__ sums,
                                                float* __restrict__ out, int nsl) {
    const int t = threadIdx.x;
    float acc = 0.0f;
    for (int i = t; i < 257 * NIMG; i += 256) {
        const int rr = i % 257;
        const int im = i / 257;
        float cr = 0.f, c1 = 0.f, c2 = 0.f;
        for (int s = 0; s < nsl; ++s) {
            const float* pp = sums + (size_t)(im * nsl + s) * NB3 + rr * 3;
            cr += pp[0]; c1 += pp[1]; c2 += pp[2];
        }
        float frc = fabsf(cr) / (sqrtf(c1 * c2) + 1e-8f);
        float d = 1.0f - frc;
        acc += d * d;
    }
#pragma unroll
    for (int off = 32; off > 0; off >>= 1) acc += __shfl_down(acc, off);
    __shared__ float red[4];
    if ((t & 63) == 0) red[t >> 6] = acc;
    __syncthreads();
    if (t == 0)
        out[0] = (red[0] + red[1] + red[2] + red[3]) * (1.0f / (257.0f * (float)NIMG));
}

// ---------------------------------------------------------------------------
extern "C" void kernel_launch(void* const* d_in, const int* in_sizes, int n_in,
                              void* d_out, int out_size, void* d_ws, size_t ws_size,
                              hipStream_t stream) {
    const float* xr = (const float*)d_in[0];   // output: 32x1x512x512 f32
    const float* yr = (const float*)d_in[1];   // target: 32x1x512x512 f32

    float2* Zt = (float2*)d_ws;                                    // 64 MiB
    const size_t ztBytes = ((size_t)NIMG << 18) * sizeof(float2);
    float* sums = (float*)((char*)d_ws + ztBytes);
    const int big = (ws_size >= ztBytes + (size_t)2048 * NB3 * sizeof(float)) ? 1 : 0;

    fft_rows_T    <<<dim3(NIMG * 64), dim3(256), 0, stream>>>(xr, yr, Zt, sums, big);
    fft_cols_rings<<<dim3(NIMG * 64), dim3(256), 0, stream>>>(Zt, sums, big);
    finalize      <<<dim3(1), dim3(256), 0, stream>>>(sums, (float*)d_out, big ? 64 : 8);
}